// Round 2
// baseline (625.821 us; speedup 1.0000x reference)
//
#include <hip/hip_runtime.h>

typedef unsigned short u16;
typedef __bf16 bf16x8 __attribute__((ext_vector_type(8)));
typedef float f32x4 __attribute__((ext_vector_type(4)));
typedef u16 u16x8 __attribute__((ext_vector_type(8)));

#define MFMA16(a, b, c) __builtin_amdgcn_mfma_f32_16x16x32_bf16(a, b, c, 0, 0, 0)

__device__ inline u16 f2bf(float f) {
  union { float f; unsigned u; } x; x.f = f;
  unsigned r = x.u + 0x7FFF + ((x.u >> 16) & 1);  // RNE
  return (u16)(r >> 16);
}

__device__ inline bf16x8 ld_frag_lds(const u16* p) {
  return __builtin_bit_cast(bf16x8, *(const u16x8*)p);
}

// NaN-propagating relu: wrong-dtype garbage shows up as huge absmax, not silent 0.
__device__ inline float relu_diag(float v) {
  return (v != v || v > 0.f) ? v : 0.f;
}

// ---------------------------------------------------------------------------
// QKV projection GEMM: out = relu(A @ W), A fp32 [8192,1024], W fp32 [1024,1024].
// Output scattered bf16 to per-head layout out[((b*16+h)*2048+s)*64+d].
// Block: 256 thr (4 waves 2x2), tile 128x128, BK=32.
// ---------------------------------------------------------------------------
__launch_bounds__(256)
__global__ void gemm_qkv(const float* __restrict__ A, const float* __restrict__ W,
                         u16* __restrict__ out) {
  __shared__ u16 Asm[128 * 40];  // [m][k] bf16, ld 40 pad
  __shared__ u16 Bsm[128 * 40];  // [n][k] bf16, transposed

  const int tid = threadIdx.x;
  const int lane = tid & 63, l15 = lane & 15, quad = lane >> 4;
  const int w = tid >> 6, wm = w & 1, wn = w >> 1;
  const int m0 = blockIdx.y * 128, n0 = blockIdx.x * 128;

  f32x4 acc[4][4] = {};

  const int ar = tid >> 1, as = (tid & 1) * 16;  // A: 128 rows x 32 k
  const int bk = tid >> 3, bs = (tid & 7) * 16;  // W: 32 k-rows x 128 n

  for (int k0 = 0; k0 < 1024; k0 += 32) {
    __syncthreads();
    // A tile: fp32 -> bf16 -> LDS
    const float* Ag = A + (size_t)(m0 + ar) * 1024 + k0 + as;
    float fa[16];
#pragma unroll
    for (int i = 0; i < 4; ++i) *(float4*)&fa[i * 4] = ((const float4*)Ag)[i];
    u16x8 lo, hi;
#pragma unroll
    for (int i = 0; i < 8; ++i) { lo[i] = f2bf(fa[i]); hi[i] = f2bf(fa[i + 8]); }
    *(u16x8*)&Asm[ar * 40 + as]     = lo;
    *(u16x8*)&Asm[ar * 40 + as + 8] = hi;
    // W tile: fp32 -> bf16 -> LDS transposed ([k][n] -> [n][k])
    const float* Wg = W + (size_t)(k0 + bk) * 1024 + n0 + bs;
    float fw[16];
#pragma unroll
    for (int i = 0; i < 4; ++i) *(float4*)&fw[i * 4] = ((const float4*)Wg)[i];
#pragma unroll
    for (int i = 0; i < 16; ++i) Bsm[(bs + i) * 40 + bk] = f2bf(fw[i]);
    __syncthreads();

    bf16x8 a[4], b[4];
#pragma unroll
    for (int i = 0; i < 4; ++i)
      a[i] = ld_frag_lds(&Asm[(wm * 64 + i * 16 + l15) * 40 + quad * 8]);
#pragma unroll
    for (int j = 0; j < 4; ++j)
      b[j] = ld_frag_lds(&Bsm[(wn * 64 + j * 16 + l15) * 40 + quad * 8]);
#pragma unroll
    for (int i = 0; i < 4; ++i)
#pragma unroll
      for (int j = 0; j < 4; ++j)
        acc[i][j] = MFMA16(a[i], b[j], acc[i][j]);
  }

  // Epilogue: relu + scatter bf16. C layout: row = quad*4+reg, col = l15.
#pragma unroll
  for (int i = 0; i < 4; ++i)
#pragma unroll
    for (int j = 0; j < 4; ++j)
#pragma unroll
      for (int r = 0; r < 4; ++r) {
        float v = relu_diag(acc[i][j][r]);
        int m = m0 + wm * 64 + i * 16 + quad * 4 + r;
        int n = n0 + wn * 64 + j * 16 + l15;
        size_t idx = ((size_t)(((m >> 11) * 16 + (n >> 6)) * 2048 + (m & 2047))) * 64 + (n & 63);
        out[idx] = f2bf(v);
      }
}

// ---------------------------------------------------------------------------
// Output GEMM: out = relu(ctx @ Wo), ctx bf16 [8192,1024] (ws), Wo fp32, out fp32.
// ---------------------------------------------------------------------------
__launch_bounds__(256)
__global__ void gemm_out(const u16* __restrict__ A, const float* __restrict__ W,
                         float* __restrict__ out) {
  __shared__ u16 Asm[128 * 40];
  __shared__ u16 Bsm[128 * 40];

  const int tid = threadIdx.x;
  const int lane = tid & 63, l15 = lane & 15, quad = lane >> 4;
  const int w = tid >> 6, wm = w & 1, wn = w >> 1;
  const int m0 = blockIdx.y * 128, n0 = blockIdx.x * 128;

  f32x4 acc[4][4] = {};

  const int ar = tid >> 1, as = (tid & 1) * 16;
  const int bk = tid >> 3, bs = (tid & 7) * 16;

  for (int k0 = 0; k0 < 1024; k0 += 32) {
    __syncthreads();
    const u16* Ag = A + (size_t)(m0 + ar) * 1024 + k0 + as;
    *(u16x8*)&Asm[ar * 40 + as]     = *(const u16x8*)(Ag);
    *(u16x8*)&Asm[ar * 40 + as + 8] = *(const u16x8*)(Ag + 8);
    const float* Wg = W + (size_t)(k0 + bk) * 1024 + n0 + bs;
    float fw[16];
#pragma unroll
    for (int i = 0; i < 4; ++i) *(float4*)&fw[i * 4] = ((const float4*)Wg)[i];
#pragma unroll
    for (int i = 0; i < 16; ++i) Bsm[(bs + i) * 40 + bk] = f2bf(fw[i]);
    __syncthreads();

    bf16x8 a[4], b[4];
#pragma unroll
    for (int i = 0; i < 4; ++i)
      a[i] = ld_frag_lds(&Asm[(wm * 64 + i * 16 + l15) * 40 + quad * 8]);
#pragma unroll
    for (int j = 0; j < 4; ++j)
      b[j] = ld_frag_lds(&Bsm[(wn * 64 + j * 16 + l15) * 40 + quad * 8]);
#pragma unroll
    for (int i = 0; i < 4; ++i)
#pragma unroll
      for (int j = 0; j < 4; ++j)
        acc[i][j] = MFMA16(a[i], b[j], acc[i][j]);
  }

#pragma unroll
  for (int i = 0; i < 4; ++i)
#pragma unroll
    for (int j = 0; j < 4; ++j)
#pragma unroll
      for (int r = 0; r < 4; ++r) {
        float v = relu_diag(acc[i][j][r]);
        int m = m0 + wm * 64 + i * 16 + quad * 4 + r;
        int n = n0 + wn * 64 + j * 16 + l15;
        out[(size_t)m * 1024 + n] = v;
      }
}

// ---------------------------------------------------------------------------
// Flash attention. Q,K,V: [64 bh][2048 s][64 d] bf16 (ws). ctx: [8192][1024] bf16.
// One WG per (bh, 64-query tile); 4 waves x 16 queries; 32 K-tiles of 64 keys.
// ---------------------------------------------------------------------------
__launch_bounds__(256)
__global__ void attn(const u16* __restrict__ Q, const u16* __restrict__ K,
                     const u16* __restrict__ V, u16* __restrict__ ctx) {
  __shared__ u16 Ksm[64 * 72];      // [key][d]
  __shared__ u16 Vsm[64 * 72];      // [d][key] (transposed during staging)
  __shared__ u16 Psm[4][16 * 72];   // per-wave P tile [q][key]

  const int tid = threadIdx.x;
  const int lane = tid & 63, l15 = lane & 15, quad = lane >> 4;
  const int w = tid >> 6;
  const int bh = blockIdx.y;
  const int q0 = blockIdx.x * 64;
  const u16* Qp = Q + (size_t)bh * 2048 * 64;
  const u16* Kp = K + (size_t)bh * 2048 * 64;
  const u16* Vp = V + (size_t)bh * 2048 * 64;

  // Q A-frags (reused across all K-tiles): A[m=l15][k=quad*8+j]
  bf16x8 aq[2];
#pragma unroll
  for (int kk = 0; kk < 2; ++kk)
    aq[kk] = __builtin_bit_cast(
        bf16x8, *(const u16x8*)(Qp + (size_t)(q0 + w * 16 + l15) * 64 + kk * 32 + quad * 8));

  f32x4 o[4] = {};
  float mrow[4], lrow[4];
#pragma unroll
  for (int r = 0; r < 4; ++r) { mrow[r] = -1e30f; lrow[r] = 0.f; }

  const int sr = tid >> 2, ss = (tid & 3) * 16;  // staging: 64 rows x 64 cols

  for (int k0 = 0; k0 < 2048; k0 += 64) {
    __syncthreads();
    const u16* Kg = Kp + (size_t)(k0 + sr) * 64 + ss;
    *(u16x8*)&Ksm[sr * 72 + ss]     = *(const u16x8*)(Kg);
    *(u16x8*)&Ksm[sr * 72 + ss + 8] = *(const u16x8*)(Kg + 8);
    const u16* Vg = Vp + (size_t)(k0 + sr) * 64 + ss;
    u16x8 v0 = *(const u16x8*)(Vg);
    u16x8 v1 = *(const u16x8*)(Vg + 8);
#pragma unroll
    for (int i = 0; i < 8; ++i) Vsm[(ss + i) * 72 + sr] = v0[i];
#pragma unroll
    for (int i = 0; i < 8; ++i) Vsm[(ss + 8 + i) * 72 + sr] = v1[i];
    __syncthreads();

    // S = Q K^T / 8
    f32x4 s[4] = {};
#pragma unroll
    for (int kk = 0; kk < 2; ++kk)
#pragma unroll
      for (int j = 0; j < 4; ++j) {
        bf16x8 kb = ld_frag_lds(&Ksm[(j * 16 + l15) * 72 + kk * 32 + quad * 8]);
        s[j] = MFMA16(aq[kk], kb, s[j]);
      }
#pragma unroll
    for (int j = 0; j < 4; ++j)
#pragma unroll
      for (int r = 0; r < 4; ++r) s[j][r] *= 0.125f;

    // Online softmax (lane owns rows quad*4+r; 16 key-cols across l15 lanes)
    float alpha[4];
#pragma unroll
    for (int r = 0; r < 4; ++r) {
      float mx = fmaxf(fmaxf(s[0][r], s[1][r]), fmaxf(s[2][r], s[3][r]));
#pragma unroll
      for (int off = 1; off < 16; off <<= 1) mx = fmaxf(mx, __shfl_xor(mx, off, 64));
      float mnew = fmaxf(mrow[r], mx);
      alpha[r] = __expf(mrow[r] - mnew);
      mrow[r] = mnew;
      float rs = 0.f;
#pragma unroll
      for (int j = 0; j < 4; ++j) {
        float p = __expf(s[j][r] - mnew);
        s[j][r] = p;
        rs += p;
      }
#pragma unroll
      for (int off = 1; off < 16; off <<= 1) rs += __shfl_xor(rs, off, 64);
      lrow[r] = lrow[r] * alpha[r] + rs;
    }
    // Rescale O; P tile to per-wave LDS (C layout -> [q][key])
#pragma unroll
    for (int j = 0; j < 4; ++j)
#pragma unroll
      for (int r = 0; r < 4; ++r) {
        o[j][r] *= alpha[r];
        Psm[w][(quad * 4 + r) * 72 + j * 16 + l15] = f2bf(s[j][r]);
      }
    // PV: A-frag of P (m=q, k=key), B-frag of V^T (n=d, k=key)
#pragma unroll
    for (int kk = 0; kk < 2; ++kk) {
      bf16x8 pa = ld_frag_lds(&Psm[w][l15 * 72 + kk * 32 + quad * 8]);
#pragma unroll
      for (int j = 0; j < 4; ++j) {
        bf16x8 vb = ld_frag_lds(&Vsm[(j * 16 + l15) * 72 + kk * 32 + quad * 8]);
        o[j] = MFMA16(pa, vb, o[j]);
      }
    }
  }

  // Normalize and write ctx (bf16, row-major [b*2048+q][h*64+d])
  const int b = bh >> 4, h = bh & 15;
#pragma unroll
  for (int j = 0; j < 4; ++j)
#pragma unroll
    for (int r = 0; r < 4; ++r) {
      int q = q0 + w * 16 + quad * 4 + r;
      float v = o[j][r] / lrow[r];
      int col = h * 64 + j * 16 + l15;
      ctx[(size_t)(b * 2048 + q) * 1024 + col] = f2bf(v);
    }
}

// ---------------------------------------------------------------------------
extern "C" void kernel_launch(void* const* d_in, const int* in_sizes, int n_in,
                              void* d_out, int out_size, void* d_ws, size_t ws_size,
                              hipStream_t stream) {
  const float* query = (const float*)d_in[0];
  const float* key   = (const float*)d_in[1];
  const float* value = (const float*)d_in[2];
  const float* Wq = (const float*)d_in[3];
  const float* Wk = (const float*)d_in[4];
  const float* Wv = (const float*)d_in[5];
  const float* Wo = (const float*)d_in[6];
  float* outp = (float*)d_out;

  const size_t NTOK = (size_t)8192 * 1024;  // 8M elements per tensor
  u16* Qw = (u16*)d_ws;          // [bh][s][d] bf16, 16MB each
  u16* Kw = Qw + NTOK;
  u16* Vw = Kw + NTOK;
  u16* Cw = Vw + NTOK;           // ctx [8192][1024] bf16

  dim3 gg(8, 64), gb(256);
  gemm_qkv<<<gg, gb, 0, stream>>>(query, Wq, Qw);
  gemm_qkv<<<gg, gb, 0, stream>>>(key,   Wk, Kw);
  gemm_qkv<<<gg, gb, 0, stream>>>(value, Wv, Vw);
  attn<<<dim3(32, 64), gb, 0, stream>>>(Qw, Kw, Vw, Cw);
  gemm_out<<<gg, gb, 0, stream>>>(Cw, Wo, outp);
}

// Round 3
// 503.776 us; speedup vs baseline: 1.2423x; 1.2423x over previous
//
#include <hip/hip_runtime.h>

typedef unsigned short u16;
typedef __bf16 bf16x8 __attribute__((ext_vector_type(8)));
typedef float f32x4 __attribute__((ext_vector_type(4)));
typedef u16 u16x8 __attribute__((ext_vector_type(8)));
typedef u16 u16x4 __attribute__((ext_vector_type(4)));

#define MFMA16(a, b, c) __builtin_amdgcn_mfma_f32_16x16x32_bf16(a, b, c, 0, 0, 0)

__device__ inline u16 f2bf(float f) {
  union { float f; unsigned u; } x; x.f = f;
  unsigned r = x.u + 0x7FFF + ((x.u >> 16) & 1);  // RNE
  return (u16)(r >> 16);
}
__device__ inline u16 cvt_bf(float f) {  // native cvt (packs to v_cvt_pk_bf16_f32)
  __bf16 h = (__bf16)f; return __builtin_bit_cast(u16, h);
}
__device__ inline bf16x8 ld_frag(const u16* p) {
  return __builtin_bit_cast(bf16x8, *(const u16x8*)p);
}
// async global->LDS, 16B per lane; lds dest = wave-uniform base + lane*16
__device__ inline void dma16(const u16* g, u16* l) {
  __builtin_amdgcn_global_load_lds(
      (const __attribute__((address_space(1))) unsigned*)g,
      (__attribute__((address_space(3))) unsigned*)l, 16, 0, 0);
}

// ---------------------------------------------------------------------------
// Weight transpose-convert: W[k][n] fp32 -> Wt[n][k] bf16. z selects weight.
// ---------------------------------------------------------------------------
__launch_bounds__(256)
__global__ void prep_w(const float* __restrict__ Wq, const float* __restrict__ Wk,
                       const float* __restrict__ Wv, const float* __restrict__ Wo,
                       u16* __restrict__ Wt) {
  __shared__ u16 T[64 * 72];
  const int z = blockIdx.z;
  const float* W = z == 0 ? Wq : z == 1 ? Wk : z == 2 ? Wv : Wo;
  u16* D = Wt + ((size_t)z << 20);
  const int k0 = blockIdx.y * 64, c0 = blockIdx.x * 64;
  const int tid = threadIdx.x;
  const int kr = tid >> 2, cs = (tid & 3) * 16;
  const float* src = W + (size_t)(k0 + kr) * 1024 + c0 + cs;
  float f[16];
#pragma unroll
  for (int i = 0; i < 4; ++i) *(float4*)&f[i * 4] = ((const float4*)src)[i];
#pragma unroll
  for (int i = 0; i < 16; ++i) T[(cs + i) * 72 + kr] = cvt_bf(f[i]);
  __syncthreads();
  const int nn = tid >> 2, ks = (tid & 3) * 16;
  u16* dst = D + (size_t)(c0 + nn) * 1024 + k0 + ks;
  *(u16x8*)dst = *(u16x8*)&T[nn * 72 + ks];
  *(u16x8*)(dst + 8) = *(u16x8*)&T[nn * 72 + ks + 8];
}

// ---------------------------------------------------------------------------
// QKV GEMM: relu(A @ W) ; A fp32 [8192,1024] (cvt staging), Wt bf16 [n][k] (DMA).
// z=0: Q -> [bh][s][d]; z=1: K -> [bh][s][d]; z=2: V -> [bh][d][s] (LDS-transposed
// epilogue for coalesced stores). LDS chunk layout [kc][m] for conflict-free b128.
// ---------------------------------------------------------------------------
__launch_bounds__(256)
__global__ void gemm_fwd(const float* __restrict__ Aq, const float* __restrict__ Ak,
                         const float* __restrict__ Av, const u16* __restrict__ Wt,
                         u16* __restrict__ Qw, u16* __restrict__ Kw,
                         u16* __restrict__ Vw) {
  __shared__ u16 smem[8704];  // A chunks [0,4096), B chunks [4096,8192); epi reuse
  u16* Asm = smem;
  u16* Bsm = smem + 4096;
  const int z = blockIdx.z;
  const float* A = z == 0 ? Aq : z == 1 ? Ak : Av;
  const u16* Bt = Wt + ((size_t)z << 20);
  u16* out = z == 0 ? Qw : z == 1 ? Kw : Vw;

  const int tid = threadIdx.x;
  const int lane = tid & 63, l15 = lane & 15, quad = lane >> 4;
  const int wv = tid >> 6, wm = wv & 1, wn = wv >> 1;
  const int m0 = blockIdx.y * 128, n0 = blockIdx.x * 128;

  f32x4 acc[4][4] = {};

  for (int k0 = 0; k0 < 1024; k0 += 32) {
    __syncthreads();
    // B: DMA 512 chunks (16B), chunk c -> (n=c&127, kc=c>>7), LDS addr c*16B
#pragma unroll
    for (int t = 0; t < 2; ++t) {
      const int cb = t * 256 + wv * 64;
      const int c = cb + lane, n = c & 127, kc = c >> 7;
      dma16(Bt + (size_t)(n0 + n) * 1024 + k0 + kc * 8, &Bsm[cb * 8]);
    }
    // A: fp32 -> bf16 cvt staging into same chunk layout
#pragma unroll
    for (int t = 0; t < 2; ++t) {
      const int c = t * 256 + tid, m = c & 127, kc = c >> 7;
      const float* ag = A + (size_t)(m0 + m) * 1024 + k0 + kc * 8;
      float4 f0 = *(const float4*)ag, f1 = *(const float4*)(ag + 4);
      u16x8 h;
      h[0] = cvt_bf(f0.x); h[1] = cvt_bf(f0.y); h[2] = cvt_bf(f0.z); h[3] = cvt_bf(f0.w);
      h[4] = cvt_bf(f1.x); h[5] = cvt_bf(f1.y); h[6] = cvt_bf(f1.z); h[7] = cvt_bf(f1.w);
      *(u16x8*)&Asm[c * 8] = h;
    }
    __syncthreads();

    bf16x8 a[4], b[4];
#pragma unroll
    for (int i = 0; i < 4; ++i)
      a[i] = ld_frag(&Asm[(quad * 128 + wm * 64 + i * 16 + l15) * 8]);
#pragma unroll
    for (int j = 0; j < 4; ++j)
      b[j] = ld_frag(&Bsm[(quad * 128 + wn * 64 + j * 16 + l15) * 8]);
#pragma unroll
    for (int i = 0; i < 4; ++i)
#pragma unroll
      for (int j = 0; j < 4; ++j)
        acc[i][j] = MFMA16(a[i], b[j], acc[i][j]);
  }

  if (z < 2) {
    // scatter to [bh][s][d]; C layout: row = quad*4+r, col = l15
#pragma unroll
    for (int i = 0; i < 4; ++i)
#pragma unroll
      for (int j = 0; j < 4; ++j)
#pragma unroll
        for (int r = 0; r < 4; ++r) {
          float v = fmaxf(acc[i][j][r], 0.f);
          int m = m0 + wm * 64 + i * 16 + quad * 4 + r;
          int n = n0 + wn * 64 + j * 16 + l15;
          size_t idx =
              ((size_t)(((m >> 11) * 16 + (n >> 6)) * 2048 + (m & 2047))) * 64 + (n & 63);
          out[idx] = f2bf(v);
        }
  } else {
    // V: transpose through LDS -> Vt[bh][d][s], coalesced row stores
    const int b = m0 >> 11, s0 = m0 & 2047;
#pragma unroll
    for (int half = 0; half < 2; ++half) {
      __syncthreads();
      if (wn == half) {
#pragma unroll
        for (int i = 0; i < 4; ++i)
#pragma unroll
          for (int j = 0; j < 4; ++j) {
            u16x4 pk;
#pragma unroll
            for (int r = 0; r < 4; ++r) pk[r] = f2bf(fmaxf(acc[i][j][r], 0.f));
            const int nn = j * 16 + l15;
            const int ml = wm * 64 + i * 16 + quad * 4;
            *(u16x4*)&smem[nn * 136 + ml] = pk;  // ld=136 u16 (272B, 16B-mult)
          }
      }
      __syncthreads();
      const int h = (n0 + half * 64) >> 6;
      const int nn = tid >> 2, seg = (tid & 3) * 32;
      u16* dst = out + ((size_t)((b * 16 + h) * 64 + nn)) * 2048 + s0 + seg;
#pragma unroll
      for (int i2 = 0; i2 < 4; ++i2)
        *(u16x8*)&dst[i2 * 8] = *(u16x8*)&smem[nn * 136 + seg + i2 * 8];
    }
  }
}

// ---------------------------------------------------------------------------
// Output GEMM: relu(ctx @ Wo); ctx bf16 [8192,1024] DMA, Wot bf16 [n][k] DMA,
// out fp32 row-major.
// ---------------------------------------------------------------------------
__launch_bounds__(256)
__global__ void gemm_out(const u16* __restrict__ A, const u16* __restrict__ Bt,
                         float* __restrict__ out) {
  __shared__ u16 smem[8192];
  u16* Asm = smem;
  u16* Bsm = smem + 4096;
  const int tid = threadIdx.x;
  const int lane = tid & 63, l15 = lane & 15, quad = lane >> 4;
  const int wv = tid >> 6, wm = wv & 1, wn = wv >> 1;
  const int m0 = blockIdx.y * 128, n0 = blockIdx.x * 128;
  f32x4 acc[4][4] = {};

  for (int k0 = 0; k0 < 1024; k0 += 32) {
    __syncthreads();
#pragma unroll
    for (int t = 0; t < 2; ++t) {
      const int cb = t * 256 + wv * 64;
      const int c = cb + lane, mn = c & 127, kc = c >> 7;
      dma16(A + (size_t)(m0 + mn) * 1024 + k0 + kc * 8, &Asm[cb * 8]);
      dma16(Bt + (size_t)(n0 + mn) * 1024 + k0 + kc * 8, &Bsm[cb * 8]);
    }
    __syncthreads();
    bf16x8 a[4], b[4];
#pragma unroll
    for (int i = 0; i < 4; ++i)
      a[i] = ld_frag(&Asm[(quad * 128 + wm * 64 + i * 16 + l15) * 8]);
#pragma unroll
    for (int j = 0; j < 4; ++j)
      b[j] = ld_frag(&Bsm[(quad * 128 + wn * 64 + j * 16 + l15) * 8]);
#pragma unroll
    for (int i = 0; i < 4; ++i)
#pragma unroll
      for (int j = 0; j < 4; ++j)
        acc[i][j] = MFMA16(a[i], b[j], acc[i][j]);
  }
#pragma unroll
  for (int i = 0; i < 4; ++i)
#pragma unroll
    for (int j = 0; j < 4; ++j)
#pragma unroll
      for (int r = 0; r < 4; ++r) {
        int m = m0 + wm * 64 + i * 16 + quad * 4 + r;
        int n = n0 + wn * 64 + j * 16 + l15;
        out[(size_t)m * 1024 + n] = fmaxf(acc[i][j][r], 0.f);
      }
}

// ---------------------------------------------------------------------------
// Flash attention, fixed-shift softmax (scores >= 0, shift C=10).
// Q,K: [64 bh][2048 s][64 d]; Vt: [64 bh][64 d][2048 s]; all bf16, all DMA-staged.
// Block: 4 waves x 16 q, K-tile = 128 keys.
// ---------------------------------------------------------------------------
__launch_bounds__(256)
__global__ void attn(const u16* __restrict__ Q, const u16* __restrict__ K,
                     const u16* __restrict__ Vt, u16* __restrict__ ctx) {
  __shared__ u16 Ksm[8192];        // chunks [dc(8)][key(128)]
  __shared__ u16 Vsm[8192];        // chunks [kc(16)][d(64)]
  __shared__ u16 Psm[4][16 * 136]; // per-wave [q][key], ld=136

  const int tid = threadIdx.x;
  const int lane = tid & 63, l15 = lane & 15, quad = lane >> 4;
  const int wv = tid >> 6;
  const int bh = blockIdx.y;
  const int q0 = blockIdx.x * 64;
  const u16* Qp = Q + (size_t)bh * 2048 * 64;
  const u16* Kp = K + (size_t)bh * 2048 * 64;
  const u16* Vp = Vt + (size_t)bh * 64 * 2048;

  bf16x8 aq[2];
#pragma unroll
  for (int kk = 0; kk < 2; ++kk)
    aq[kk] = __builtin_bit_cast(
        bf16x8, *(const u16x8*)(Qp + (size_t)(q0 + wv * 16 + l15) * 64 + kk * 32 + quad * 8));

  f32x4 o[4] = {};
  float lsum[4] = {0.f, 0.f, 0.f, 0.f};

  for (int k0 = 0; k0 < 2048; k0 += 128) {
    __syncthreads();
#pragma unroll
    for (int t = 0; t < 4; ++t) {
      const int cb = t * 256 + wv * 64;
      const int c = cb + lane;
      const int key = c & 127, dc = c >> 7;
      dma16(Kp + (size_t)(k0 + key) * 64 + dc * 8, &Ksm[cb * 8]);
      const int d = c & 63, kc = c >> 6;
      dma16(Vp + (size_t)d * 2048 + k0 + kc * 8, &Vsm[cb * 8]);
    }
    __syncthreads();

    // S = relu(Q)relu(K)^T (raw); scale+shift folded into exp
    f32x4 s[8] = {};
#pragma unroll
    for (int kk = 0; kk < 2; ++kk)
#pragma unroll
      for (int j = 0; j < 8; ++j) {
        bf16x8 kb = ld_frag(&Ksm[((kk * 4 + quad) * 128 + j * 16 + l15) * 8]);
        s[j] = MFMA16(aq[kk], kb, s[j]);
      }

    // p = exp(s/8 - 10); accumulate row-sums locally (no per-tile shuffles)
#pragma unroll
    for (int j = 0; j < 8; ++j)
#pragma unroll
      for (int r = 0; r < 4; ++r) {
        float p = __expf(fmaf(s[j][r], 0.125f, -10.f));
        lsum[r] += p;
        Psm[wv][(quad * 4 + r) * 136 + j * 16 + l15] = cvt_bf(p);
      }

    // PV: A-frag of P [q=l15][k=key], B-frag of Vt [d=l15][k=key]
#pragma unroll
    for (int kk = 0; kk < 4; ++kk) {
      bf16x8 pa = ld_frag(&Psm[wv][l15 * 136 + kk * 32 + quad * 8]);
#pragma unroll
      for (int j = 0; j < 4; ++j) {
        bf16x8 vb = ld_frag(&Vsm[((kk * 4 + quad) * 64 + j * 16 + l15) * 8]);
        o[j] = MFMA16(pa, vb, o[j]);
      }
    }
  }

  // One reduction at the end: sum l over the 16 column-lanes
#pragma unroll
  for (int r = 0; r < 4; ++r) {
#pragma unroll
    for (int off = 1; off < 16; off <<= 1) lsum[r] += __shfl_xor(lsum[r], off, 64);
  }
  float inv[4];
#pragma unroll
  for (int r = 0; r < 4; ++r) inv[r] = 1.f / lsum[r];

  const int b = bh >> 4, h = bh & 15;
#pragma unroll
  for (int j = 0; j < 4; ++j)
#pragma unroll
    for (int r = 0; r < 4; ++r) {
      int q = q0 + wv * 16 + quad * 4 + r;
      ctx[(size_t)(b * 2048 + q) * 1024 + h * 64 + j * 16 + l15] = f2bf(o[j][r] * inv[r]);
    }
}

// ---------------------------------------------------------------------------
extern "C" void kernel_launch(void* const* d_in, const int* in_sizes, int n_in,
                              void* d_out, int out_size, void* d_ws, size_t ws_size,
                              hipStream_t stream) {
  const float* query = (const float*)d_in[0];
  const float* key   = (const float*)d_in[1];
  const float* value = (const float*)d_in[2];
  const float* Wq = (const float*)d_in[3];
  const float* Wk = (const float*)d_in[4];
  const float* Wv = (const float*)d_in[5];
  const float* Wo = (const float*)d_in[6];
  float* outp = (float*)d_out;

  // ws layout (u16 units): Wt 4x1Mi | Qw 8Mi | Kw 8Mi | Vt 8Mi | ctx 8Mi = 72MB
  u16* Wt = (u16*)d_ws;
  u16* Qw = Wt + ((size_t)4 << 20);
  u16* Kw = Qw + ((size_t)8 << 20);
  u16* Vw = Kw + ((size_t)8 << 20);
  u16* Cw = Vw + ((size_t)8 << 20);

  prep_w<<<dim3(16, 16, 4), 256, 0, stream>>>(Wq, Wk, Wv, Wo, Wt);
  gemm_fwd<<<dim3(8, 64, 3), 256, 0, stream>>>(query, key, value, Wt, Qw, Kw, Vw);
  attn<<<dim3(32, 64), 256, 0, stream>>>(Qw, Kw, Vw, Cw);
  gemm_out<<<dim3(8, 64), 256, 0, stream>>>(Cw, Wt + ((size_t)3 << 20), outp);
}